// Round 2
// baseline (1112.417 us; speedup 1.0000x reference)
//
#include <hip/hip_runtime.h>
#include <hip/hip_bf16.h>

#define N_TOK   8192
#define DIM     1024
#define HID     2048
#define NEXP    8
#define NSH     2
#define NSLOT   32768       // 2*N shared slots + 2*N routed slots
#define NPAD    128
#define MAXTILE 264

typedef unsigned int   u32;
typedef unsigned short u16;
typedef float  f32x4  __attribute__((ext_vector_type(4)));
typedef short  bf16x8 __attribute__((ext_vector_type(8)));

// ---------- workspace layout (bytes) ----------
#define OFF_CTRL  0u            // int counts[8], cursors[8], off_e[8], ntiles @24
#define OFF_DESC  256u          // int4 desc[280]
#define OFF_TOK   8192u         // int   tok[NSLOT+NPAD]
#define OFF_WSC   139776u       // float wsc[NSLOT+NPAD]
#define OFF_TOPI  271360u       // int2  topi[N_TOK]
#define OFF_PROB  336896u       // float2 probs[N_TOK]
#define OFF_XB    402432u       // u16 x_bf16[N*D]
#define OFF_W1T   17179648u     // u16 w1t[E][H][D]
#define OFF_W2T   50734080u     // u16 w2t[E][D][H]
#define OFF_SW1T  84288512u     // u16 sw1t[S][H][D]
#define OFF_SW2T  92677120u     // u16 sw2t[S][D][H]
#define OFF_H     101065728u    // u16 h[(NSLOT+NPAD)][H]

__device__ __forceinline__ u16 f2bf(float f) {
  union { float f; u32 u; } v; v.f = f;
  u32 r = v.u + 0x7FFFu + ((v.u >> 16) & 1u);
  return (u16)(r >> 16);
}

__device__ __forceinline__ float gelu_exact(float x) {
  return 0.5f * x * (1.0f + erff(x * 0.70710678118654752f));
}

__device__ __forceinline__ void gll16(const void* g, void* l) {
  __builtin_amdgcn_global_load_lds((const __attribute__((address_space(1))) u32*)g,
                                   (__attribute__((address_space(3))) u32*)l, 16, 0, 0);
}

// ---------- fp32 -> bf16 straight cast ----------
__global__ void cvt_bf16_kernel(const float* __restrict__ in, u16* __restrict__ out, int n4) {
  int i = blockIdx.x * blockDim.x + threadIdx.x;
  if (i >= n4) return;
  float4 v = ((const float4*)in)[i];
  ushort4 o;
  o.x = f2bf(v.x); o.y = f2bf(v.y); o.z = f2bf(v.z); o.w = f2bf(v.w);
  ((ushort4*)out)[i] = o;
}

// ---------- fp32 [B][R][C] -> bf16 [B][C][R] ----------
__global__ void transpose_cvt_kernel(const float* __restrict__ in, u16* __restrict__ out,
                                     int R, int C) {
  __shared__ float t[32][33];
  int b = blockIdx.z;
  const float* ip = in + (size_t)b * R * C;
  u16* op = out + (size_t)b * R * C;
  int c0 = blockIdx.x * 32, r0 = blockIdx.y * 32;
  int tx = threadIdx.x, ty = threadIdx.y;  // block (32,8)
#pragma unroll
  for (int i = 0; i < 4; i++) {
    int r = ty + i * 8;
    t[r][tx] = ip[(size_t)(r0 + r) * C + c0 + tx];
  }
  __syncthreads();
#pragma unroll
  for (int i = 0; i < 4; i++) {
    int c = ty + i * 8;
    op[(size_t)(c0 + c) * R + r0 + tx] = f2bf(t[tx][c]);
  }
}

// ---------- router: fp32 gates, top-2 + softmax, per-expert counts ----------
__global__ __launch_bounds__(64) void router_kernel(
    const float* __restrict__ x, const float* __restrict__ rw, const float* __restrict__ rb,
    int* __restrict__ ctrl, int2* __restrict__ topi, float2* __restrict__ probs) {
  int n = blockIdx.x, lane = threadIdx.x;
  float acc[NEXP];
#pragma unroll
  for (int e = 0; e < NEXP; e++) acc[e] = 0.f;
  const float* xrow = x + (size_t)n * DIM;
  for (int i = 0; i < DIM / 64; i++) {
    int d = i * 64 + lane;
    float xv = xrow[d];
    const float4* r4 = (const float4*)(rw + (size_t)d * NEXP);
    float4 a = r4[0], b = r4[1];
    acc[0] += xv * a.x; acc[1] += xv * a.y; acc[2] += xv * a.z; acc[3] += xv * a.w;
    acc[4] += xv * b.x; acc[5] += xv * b.y; acc[6] += xv * b.z; acc[7] += xv * b.w;
  }
#pragma unroll
  for (int e = 0; e < NEXP; e++) {
    float v = acc[e];
    for (int off = 32; off > 0; off >>= 1) v += __shfl_down(v, off);
    acc[e] = v;
  }
  if (lane == 0) {
    float g[NEXP];
#pragma unroll
    for (int e = 0; e < NEXP; e++) g[e] = acc[e] + rb[e];
    int i0 = 0; float v0 = g[0];
#pragma unroll
    for (int e = 1; e < NEXP; e++) if (g[e] > v0) { v0 = g[e]; i0 = e; }
    int i1 = -1; float v1 = -1e30f;
#pragma unroll
    for (int e = 0; e < NEXP; e++) if (e != i0 && g[e] > v1) { v1 = g[e]; i1 = e; }
    float e1 = expf(v1 - v0);
    float p0 = 1.f / (1.f + e1);
    float p1 = 1.f - p0;
    topi[n]  = make_int2(i0, i1);
    probs[n] = make_float2(p0, p1);
    atomicAdd(&ctrl[i0], 1);
    atomicAdd(&ctrl[i1], 1);
  }
}

// ---------- plan: offsets + tile descriptors ----------
__global__ void plan_kernel(int* __restrict__ ctrl, int4* __restrict__ desc) {
  int nt = 0;
  for (int s = 0; s < NSH; s++)
    for (int i = 0; i < N_TOK / 128; i++)
      desc[nt++] = make_int4(s, s * N_TOK + i * 128, 128, 0);
  int off = 0;
  for (int e = 0; e < NEXP; e++) {
    int cnt = ctrl[e];
    ctrl[16 + e] = off;
    int base = 2 * N_TOK + off;
    for (int i = 0; i * 128 < cnt; i++) {
      int rows = cnt - i * 128; if (rows > 128) rows = 128;
      desc[nt++] = make_int4(2 + e, base + i * 128, rows, 0);
    }
    off += cnt;
  }
  ctrl[24] = nt;
}

// ---------- assign: fill token/scale slot arrays ----------
__global__ void assign_kernel(const int2* __restrict__ topi, const float2* __restrict__ probs,
                              int* __restrict__ ctrl, int* __restrict__ tok,
                              float* __restrict__ wsc) {
  int n = blockIdx.x * blockDim.x + threadIdx.x;
  if (n >= N_TOK) return;
  tok[n] = n;           wsc[n] = 0.5f;
  tok[N_TOK + n] = n;   wsc[N_TOK + n] = 0.5f;
  int2 ti = topi[n]; float2 p = probs[n];
  int pos  = atomicAdd(&ctrl[8 + ti.x], 1);
  int slot = 2 * N_TOK + ctrl[16 + ti.x] + pos;
  tok[slot] = n; wsc[slot] = p.x;
  pos  = atomicAdd(&ctrl[8 + ti.y], 1);
  slot = 2 * N_TOK + ctrl[16 + ti.y] + pos;
  tok[slot] = n; wsc[slot] = p.y;
  if (n < NPAD) { tok[NSLOT + n] = 0; wsc[NSLOT + n] = 0.f; }
}

// ---------- GEMM1: h = gelu(gather(x) @ w1[g] + b1[g]), bf16 out ----------
__global__ __launch_bounds__(256) void gemm1_kernel(
    const u16* __restrict__ xb, const u16* __restrict__ w1t, const u16* __restrict__ sw1t,
    const float* __restrict__ b1, const float* __restrict__ sb1,
    const int* __restrict__ ctrl, const int4* __restrict__ desc,
    const int* __restrict__ tok, u16* __restrict__ hbuf) {
  int t = blockIdx.y;
  if (t >= ctrl[24]) return;
  int4 d = desc[t];
  int g = d.x, slot0 = d.y, rows = d.z;
  int n0 = blockIdx.x * 128;
  const u16* Bb = (g < NSH) ? (sw1t + (size_t)g * HID * DIM)
                            : (w1t + (size_t)(g - NSH) * HID * DIM);
  const float* bias = (g < NSH) ? (sb1 + (size_t)g * HID) : (b1 + (size_t)(g - NSH) * HID);

  __shared__ u16 As[128 * 32];
  __shared__ u16 Bs[128 * 32];
  int tid = threadIdx.x;
  int wave = tid >> 6, lane = tid & 63;
  int wm = wave >> 1, wn = wave & 1;

  int srow = tid >> 2;
  int skk  = (tid & 3) * 8;
  int tokA0 = tok[slot0 + srow];
  int tokA1 = tok[slot0 + 64 + srow];
  const u16* sA0 = xb + (size_t)tokA0 * DIM + skk;
  const u16* sA1 = xb + (size_t)tokA1 * DIM + skk;
  const u16* sB0 = Bb + (size_t)(n0 + srow) * DIM + skk;
  const u16* sB1 = Bb + (size_t)(n0 + 64 + srow) * DIM + skk;
  u16* lA0 = As + wave * 512;
  u16* lA1 = As + 2048 + wave * 512;
  u16* lB0 = Bs + wave * 512;
  u16* lB1 = Bs + 2048 + wave * 512;

  f32x4 acc[4][4];
#pragma unroll
  for (int i = 0; i < 4; i++)
#pragma unroll
    for (int j = 0; j < 4; j++)
      acc[i][j] = (f32x4){0.f, 0.f, 0.f, 0.f};

  for (int k0 = 0; k0 < DIM; k0 += 32) {
    gll16(sA0 + k0, lA0);
    gll16(sA1 + k0, lA1);
    gll16(sB0 + k0, lB0);
    gll16(sB1 + k0, lB1);
    __syncthreads();
    bf16x8 af[4], bfv[4];
#pragma unroll
    for (int i = 0; i < 4; i++)
      af[i] = *(const bf16x8*)&As[(wm * 64 + i * 16 + (lane & 15)) * 32 + (lane >> 4) * 8];
#pragma unroll
    for (int j = 0; j < 4; j++)
      bfv[j] = *(const bf16x8*)&Bs[(wn * 64 + j * 16 + (lane & 15)) * 32 + (lane >> 4) * 8];
#pragma unroll
    for (int i = 0; i < 4; i++)
#pragma unroll
      for (int j = 0; j < 4; j++)
        acc[i][j] = __builtin_amdgcn_mfma_f32_16x16x32_bf16(af[i], bfv[j], acc[i][j], 0, 0, 0);
    __syncthreads();
  }

  int lc = lane & 15, lr4 = (lane >> 4) * 4;
#pragma unroll
  for (int j = 0; j < 4; j++) {
    int col = n0 + wn * 64 + j * 16 + lc;
    float bc = bias[col];
#pragma unroll
    for (int i = 0; i < 4; i++) {
      f32x4 v = acc[i][j];
#pragma unroll
      for (int r = 0; r < 4; r++) {
        int lrow = wm * 64 + i * 16 + lr4 + r;
        if (lrow < rows)
          hbuf[(size_t)(slot0 + lrow) * HID + col] = f2bf(gelu_exact(v[r] + bc));
      }
    }
  }
}

// ---------- GEMM2: out[tok] += scale * (h @ w2[g] + b2[g]) ----------
__global__ __launch_bounds__(256) void gemm2_kernel(
    const u16* __restrict__ hbuf, const u16* __restrict__ w2t, const u16* __restrict__ sw2t,
    const float* __restrict__ b2, const float* __restrict__ sb2,
    const int* __restrict__ ctrl, const int4* __restrict__ desc,
    const int* __restrict__ tok, const float* __restrict__ wsc, float* __restrict__ out) {
  int t = blockIdx.y;
  if (t >= ctrl[24]) return;
  int4 d = desc[t];
  int g = d.x, slot0 = d.y, rows = d.z;
  int n0 = blockIdx.x * 128;
  const u16* Bb = (g < NSH) ? (sw2t + (size_t)g * HID * DIM)
                            : (w2t + (size_t)(g - NSH) * HID * DIM);
  const float* bias = (g < NSH) ? (sb2 + (size_t)g * DIM) : (b2 + (size_t)(g - NSH) * DIM);

  __shared__ u16 As[128 * 32];
  __shared__ u16 Bs[128 * 32];
  int tid = threadIdx.x;
  int wave = tid >> 6, lane = tid & 63;
  int wm = wave >> 1, wn = wave & 1;

  int srow = tid >> 2;
  int skk  = (tid & 3) * 8;
  const u16* sA0 = hbuf + (size_t)(slot0 + srow) * HID + skk;
  const u16* sA1 = hbuf + (size_t)(slot0 + 64 + srow) * HID + skk;
  const u16* sB0 = Bb + (size_t)(n0 + srow) * HID + skk;
  const u16* sB1 = Bb + (size_t)(n0 + 64 + srow) * HID + skk;
  u16* lA0 = As + wave * 512;
  u16* lA1 = As + 2048 + wave * 512;
  u16* lB0 = Bs + wave * 512;
  u16* lB1 = Bs + 2048 + wave * 512;

  f32x4 acc[4][4];
#pragma unroll
  for (int i = 0; i < 4; i++)
#pragma unroll
    for (int j = 0; j < 4; j++)
      acc[i][j] = (f32x4){0.f, 0.f, 0.f, 0.f};

  for (int k0 = 0; k0 < HID; k0 += 32) {
    gll16(sA0 + k0, lA0);
    gll16(sA1 + k0, lA1);
    gll16(sB0 + k0, lB0);
    gll16(sB1 + k0, lB1);
    __syncthreads();
    bf16x8 af[4], bfv[4];
#pragma unroll
    for (int i = 0; i < 4; i++)
      af[i] = *(const bf16x8*)&As[(wm * 64 + i * 16 + (lane & 15)) * 32 + (lane >> 4) * 8];
#pragma unroll
    for (int j = 0; j < 4; j++)
      bfv[j] = *(const bf16x8*)&Bs[(wn * 64 + j * 16 + (lane & 15)) * 32 + (lane >> 4) * 8];
#pragma unroll
    for (int i = 0; i < 4; i++)
#pragma unroll
      for (int j = 0; j < 4; j++)
        acc[i][j] = __builtin_amdgcn_mfma_f32_16x16x32_bf16(af[i], bfv[j], acc[i][j], 0, 0, 0);
    __syncthreads();
  }

  int lc = lane & 15, lr4 = (lane >> 4) * 4;
#pragma unroll
  for (int j = 0; j < 4; j++) {
    int col = n0 + wn * 64 + j * 16 + lc;
    float bc = bias[col];
#pragma unroll
    for (int i = 0; i < 4; i++) {
      f32x4 v = acc[i][j];
#pragma unroll
      for (int r = 0; r < 4; r++) {
        int lrow = wm * 64 + i * 16 + lr4 + r;
        if (lrow < rows) {
          int slot = slot0 + lrow;
          float sc = wsc[slot];
          int tk = tok[slot];
          atomicAdd(&out[(size_t)tk * DIM + col], sc * (v[r] + bc));
        }
      }
    }
  }
}

extern "C" void kernel_launch(void* const* d_in, const int* in_sizes, int n_in,
                              void* d_out, int out_size, void* d_ws, size_t ws_size,
                              hipStream_t stream) {
  const float* x   = (const float*)d_in[0];
  const float* rw  = (const float*)d_in[1];
  const float* rb  = (const float*)d_in[2];
  const float* w1  = (const float*)d_in[3];
  const float* b1  = (const float*)d_in[4];
  const float* w2  = (const float*)d_in[5];
  const float* b2  = (const float*)d_in[6];
  const float* sw1 = (const float*)d_in[7];
  const float* sb1 = (const float*)d_in[8];
  const float* sw2 = (const float*)d_in[9];
  const float* sb2 = (const float*)d_in[10];
  float* out = (float*)d_out;

  char* w = (char*)d_ws;
  int*    ctrl  = (int*)(w + OFF_CTRL);
  int4*   desc  = (int4*)(w + OFF_DESC);
  int*    tok   = (int*)(w + OFF_TOK);
  float*  wsc   = (float*)(w + OFF_WSC);
  int2*   topi  = (int2*)(w + OFF_TOPI);
  float2* probs = (float2*)(w + OFF_PROB);
  u16*    xb    = (u16*)(w + OFF_XB);
  u16*    w1t   = (u16*)(w + OFF_W1T);
  u16*    w2t   = (u16*)(w + OFF_W2T);
  u16*    sw1t  = (u16*)(w + OFF_SW1T);
  u16*    sw2t  = (u16*)(w + OFF_SW2T);
  u16*    hbuf  = (u16*)(w + OFF_H);

  hipMemsetAsync(d_out, 0, (size_t)out_size * sizeof(float), stream);
  hipMemsetAsync(d_ws, 0, 256, stream);

  // conversions / transposes
  cvt_bf16_kernel<<<(N_TOK * DIM / 4 + 255) / 256, 256, 0, stream>>>(x, xb, N_TOK * DIM / 4);
  transpose_cvt_kernel<<<dim3(HID / 32, DIM / 32, NEXP), dim3(32, 8), 0, stream>>>(w1, w1t, DIM, HID);
  transpose_cvt_kernel<<<dim3(DIM / 32, HID / 32, NEXP), dim3(32, 8), 0, stream>>>(w2, w2t, HID, DIM);
  transpose_cvt_kernel<<<dim3(HID / 32, DIM / 32, NSH), dim3(32, 8), 0, stream>>>(sw1, sw1t, DIM, HID);
  transpose_cvt_kernel<<<dim3(DIM / 32, HID / 32, NSH), dim3(32, 8), 0, stream>>>(sw2, sw2t, HID, DIM);

  // routing
  router_kernel<<<N_TOK, 64, 0, stream>>>(x, rw, rb, ctrl, topi, probs);
  plan_kernel<<<1, 1, 0, stream>>>(ctrl, desc);
  assign_kernel<<<N_TOK / 256, 256, 0, stream>>>(topi, probs, ctrl, tok, wsc);

  // grouped GEMMs
  gemm1_kernel<<<dim3(HID / 128, MAXTILE), 256, 0, stream>>>(xb, w1t, sw1t, b1, sb1,
                                                             ctrl, desc, tok, hbuf);
  gemm2_kernel<<<dim3(DIM / 128, MAXTILE), 256, 0, stream>>>(hbuf, w2t, sw2t, b2, sb2,
                                                             ctrl, desc, tok, wsc, out);
}